// Round 22
// baseline (52.258 us; speedup 1.0000x reference)
//
#include <hip/hip_runtime.h>
#include <stdint.h>

// DeformConv1d: x[8,256,4096] f32, offsets[8,1,4094,3] f32,
// weight[256,256,3] f32, bias[256] f32 -> out[8,256,4094] f32.
//
// R22: swapped-operand MFMA kills the Bp tile (and its LDS port tax).
//   D[t][o] = mfma(A = interp (lane-local, rows=t), B = weights (cols=o)).
//   - interp A-frag: lane = t, 8 consecutive c -> built straight from the
//     transposed swizzled Xt window (2 x ds_read_b128 + interp) per K16.
//     No Bp build phase, no Bp writes, NO barriers in the K-loop.
//   - weight B-frag: same lane structure as the old A-frag -> reuse
//     pack_weights_kernel + L2-hot layout verbatim.
//   - launch_bounds(512,2): VGPR cap 128 (R15/R16/R21 spilled at cap 64);
//     still 2 blocks/CU, 4 waves/SIMD.
//   - epilogue via Epi[t][o] (EPIT=65 odd -> conflict-free scalar LDS),
//     global stores keep R20's proven 256B row-segment pattern.
// Kept: burst-immediate transposed bf16 staging, register meta, XCD
// decode, grid 512 x 512.

constexpr int CIN  = 256;
constexpr int LX   = 4096;
constexpr int KT   = 3;
constexpr int OUTL = 4094;
constexpr int COUT = 256;
constexpr int NQ   = 24;    // K-chunks of 32
constexpr int EPIT = 65;    // Epi row length (o) in floats; odd -> bank-free
constexpr int NIT  = 2176;  // 128 c * 17 float4-groups per half

typedef __attribute__((ext_vector_type(8))) short bf16x8;
typedef __attribute__((ext_vector_type(4))) float f32x4;
typedef __attribute__((ext_vector_type(16))) float f32x16;

__device__ __forceinline__ short f2bf(float f) {        // round-half-up
  union { float f; uint32_t u; } v; v.f = f;
  return (short)((v.u + 0x8000u) >> 16);
}
__device__ __forceinline__ float bf2f(short s) {
  union { uint32_t u; float f; } v;
  v.u = ((uint32_t)(uint16_t)s) << 16;
  return v.f;
}
__device__ __forceinline__ float4 loadx4(const float* p, int l) {
  if (l + 3 < LX) return *(const float4*)(p + l);   // l is 16B-aligned
  float4 v; v.x = v.y = v.z = v.w = 0.f;
  if (l + 0 < LX) v.x = p[l + 0];
  if (l + 1 < LX) v.y = p[l + 1];
  if (l + 2 < LX) v.z = p[l + 2];
  return v;
}

// Weight pack (verbatim R14+): shorts idx = ((q*2+h)*8 + mf)*512 + l*8 + j
//   o = mf*32 + (l&31); c = ch*128 + (ks&3)*32 + h*16 + (l>>5)*8 + j;
//   tap = (q%12)>>2.  Used as the MFMA *B* operand now (lane&31 = o-col,
//   k = (lane>>5)*8+j) — identical lane structure to the old A-frag.
__global__ __launch_bounds__(256) void pack_weights_kernel(
    const float* __restrict__ w, short* __restrict__ ap) {
  const int gid = blockIdx.x * 256 + threadIdx.x;
  if (gid >= NQ * 2 * 8 * 64) return;
  const int l   = gid & 63;
  const int mf  = (gid >> 6) & 7;
  const int h   = (gid >> 9) & 1;
  const int q   = gid >> 10;
  const int ch  = q / 12;
  const int ks  = q % 12;
  const int tap = ks >> 2;
  const int c0  = ch * 128 + (ks & 3) * 32 + h * 16 + (l >> 5) * 8;
  const int row = mf * 32 + (l & 31);
  bf16x8 v;
  #pragma unroll
  for (int j = 0; j < 8; ++j) {
    v[j] = f2bf(w[((size_t)row * CIN + c0 + j) * KT + tap]);
  }
  *(bf16x8*)(ap + (size_t)gid * 8) = v;
}

__global__ __launch_bounds__(512, 2) void deform_gemm_kernel(
    const float* __restrict__ x, const float* __restrict__ off,
    const short* __restrict__ ap, const float* __restrict__ bias,
    float* __restrict__ out) {

  // arena: [0,17408) Xt bf16 [68][128] swz / Epi f32 [64][65] (16640B, reuse)
  //        [17408,18432) biasS
  __shared__ __align__(16) char smem[17408 + 1024];
  short* Xt    = (short*)smem;
  float* Epi   = (float*)smem;
  float* biasS = (float*)(smem + 17408);

  const int tid  = threadIdx.x;
  const int lane = tid & 63;
  const int wid  = tid >> 6;       // 0..7
  const int l31  = lane & 31;
  const int lh   = lane >> 5;      // k-half within fragment

  const int tfrag = wid & 1;       // which 32-t slab this wave computes
  const int og    = wid >> 1;      // o-group 0..3 (64 o-rows each)

  // decode: b in low 3 bits (XCD-chunk); th pairs at bid stride 8
  const int b    = blockIdx.x & 7;        // 8 batches
  const int rest = blockIdx.x >> 3;       // 0..63
  const int th   = rest & 1;              // t-half
  const int tt   = rest >> 1;             // 32 coarse t-tiles
  const int t0   = tt * 128 + th * 64;

  // ---- per-lane interp meta for THIS lane's t (= t0 + tfrag*32 + l31) ----
  float w0m[3], w1m[3];
  int   d0m[3];
  {
    const int t = t0 + tfrag * 32 + l31;
    #pragma unroll
    for (int k = 0; k < KT; ++k) {
      float w0 = 0.f, w1 = 0.f; int d0 = 0;
      if (t < OUTL) {
        const float o = off[((size_t)b * OUTL + t) * KT + k];
        float T = (float)(t + k) + o;
        T = fminf(fmaxf(T, (float)t), (float)(t + 2));  // clip to [t, t+2]
        int U0 = (int)T;                                 // floor (T >= 0)
        if (U0 > LX - 2) U0 = LX - 2;
        w1 = T - (float)U0;                              // in [0,1]
        w0 = 1.f - w1;
        d0 = U0 - t0;                                    // in [0, 66]
      }
      w0m[k] = w0; w1m[k] = w1; d0m[k] = d0;
    }
  }
  if (tid < COUT) biasS[tid] = bias[tid];

  f32x16 acc0 = {0.f,0.f,0.f,0.f,0.f,0.f,0.f,0.f,0.f,0.f,0.f,0.f,0.f,0.f,0.f,0.f};
  f32x16 acc1 = {0.f,0.f,0.f,0.f,0.f,0.f,0.f,0.f,0.f,0.f,0.f,0.f,0.f,0.f,0.f,0.f};

  const float* xb = x + (size_t)b * CIN * LX;

  #pragma unroll 1
  for (int ch = 0; ch < 2; ++ch) {
    if (ch) __syncthreads();     // ch0 K-loop's Xt readers done
    // ---- stage x window half, transposed bf16, burst-immediate ----
    #pragma unroll
    for (int r = 0; r < 5; ++r) {
      const int idx = r * 512 + tid;
      if (r < 4 || idx < NIT) {
        const int c = idx / 17, g = idx - c * 17;
        const float4 v = loadx4(xb + (size_t)(ch * 128 + c) * LX, t0 + 4 * g);
        const float fe[4] = {v.x, v.y, v.z, v.w};
        #pragma unroll
        for (int e = 0; e < 4; ++e) {
          const int pos = g * 4 + e;
          Xt[(pos * 128 + c) ^ ((pos & 7) << 3)] = f2bf(fe[e]);
        }
      }
    }
    __syncthreads();  // window (and bias on first pass) visible

    #pragma unroll
    for (int tap = 0; tap < KT; ++tap) {      // UNROLLED: static meta index
      const float w0 = w0m[tap];
      const float w1 = w1m[tap];
      const int   d0 = d0m[tap];
      const int sw0 = (d0 & 7) << 3;
      const int sw1 = ((d0 + 1) & 7) << 3;
      const int r0i = d0 * 128, r1i = (d0 + 1) * 128;

      #pragma unroll 1
      for (int csub = 0; csub < 4; ++csub) {  // NO barriers in here
        const int q = ch * 12 + tap * 4 + csub;

        // ---- interp A-frags (lane-local: lane = t, elems = c) ----
        bf16x8 aA0, aA1;
        {
          const int cs = csub * 32 + lh * 8;           // K16 half h=0
          const bf16x8 r0 = *(const bf16x8*)&Xt[(r0i + cs) ^ sw0];
          const bf16x8 r1 = *(const bf16x8*)&Xt[(r1i + cs) ^ sw1];
          #pragma unroll
          for (int j = 0; j < 8; ++j)
            aA0[j] = f2bf(bf2f(r0[j]) * w0 + bf2f(r1[j]) * w1);
        }
        {
          const int cs = csub * 32 + 16 + lh * 8;      // K16 half h=1
          const bf16x8 r0 = *(const bf16x8*)&Xt[(r0i + cs) ^ sw0];
          const bf16x8 r1 = *(const bf16x8*)&Xt[(r1i + cs) ^ sw1];
          #pragma unroll
          for (int j = 0; j < 8; ++j)
            aA1[j] = f2bf(bf2f(r0[j]) * w0 + bf2f(r1[j]) * w1);
        }

        // ---- weight B-frags (L1/L2-hot, wave-mostly-private) + MFMA ----
        const short* wq = ap + (size_t)q * 8192 + lane * 8;
        {
          const bf16x8 w00 = *(const bf16x8*)(wq + (og * 2) * 512);
          const bf16x8 w01 = *(const bf16x8*)(wq + 4096 + (og * 2) * 512);
          acc0 = __builtin_amdgcn_mfma_f32_32x32x16_bf16(aA0, w00, acc0, 0, 0, 0);
          acc0 = __builtin_amdgcn_mfma_f32_32x32x16_bf16(aA1, w01, acc0, 0, 0, 0);
        }
        {
          const bf16x8 w10 = *(const bf16x8*)(wq + (og * 2 + 1) * 512);
          const bf16x8 w11 = *(const bf16x8*)(wq + 4096 + (og * 2 + 1) * 512);
          acc1 = __builtin_amdgcn_mfma_f32_32x32x16_bf16(aA0, w10, acc1, 0, 0, 0);
          acc1 = __builtin_amdgcn_mfma_f32_32x32x16_bf16(aA1, w11, acc1, 0, 0, 0);
        }
      }
    }
  }

  // ---- epilogue: Epi[t][o] transpose tile, 4 passes of 64 o-rows ----
  // D layout (m74/m101): col = lane&31 (= o-local), row r -> t-local
  //   trow = (r&3) + 8*(r>>2) + 4*(lane>>5).
  // Producer (waves with og == p): scalar writes along o (consecutive
  // lanes -> consecutive addr, conflict-free). Consumer: per-thread 8
  // strided reads (stride EPIT=65, odd -> 2-way max), then R20's proven
  // f32x4 global stores (256B row segments).
  const size_t obase = (size_t)b * COUT * OUTL;
  #pragma unroll
  for (int p = 0; p < 4; ++p) {
    __syncthreads();   // p==0: K-loop Xt readers done; else prev pass done
    if (og == p) {
      #pragma unroll
      for (int r = 0; r < 16; ++r) {
        const int trow = (r & 3) + 8 * (r >> 2) + 4 * lh;   // 0..31
        const int tl   = tfrag * 32 + trow;                 // 0..63
        Epi[tl * EPIT + l31] = acc0[r] + biasS[p * 64 + l31];
      }
      #pragma unroll
      for (int r = 0; r < 16; ++r) {
        const int trow = (r & 3) + 8 * (r >> 2) + 4 * lh;
        const int tl   = tfrag * 32 + trow;
        Epi[tl * EPIT + 32 + l31] = acc1[r] + biasS[p * 64 + 32 + l31];
      }
    }
    __syncthreads();
    // consumer: 512 threads cover 64 o-rows x 64 t
    const int rr = tid >> 3;               // o-local 0..63
    const int c8 = (tid & 7) * 8;          // t-local 0..56
    float vals[8];
    #pragma unroll
    for (int m = 0; m < 8; ++m) vals[m] = Epi[(c8 + m) * EPIT + rr];
    const f32x4 v0 = {vals[0], vals[1], vals[2], vals[3]};
    const f32x4 v1 = {vals[4], vals[5], vals[6], vals[7]};
    float* op = out + obase + (size_t)(p * 64 + rr) * OUTL + t0 + c8;
    if (t0 + c8 + 7 < OUTL) {
      *(f32x4*)op = v0;
      *(f32x4*)(op + 4) = v1;
    } else {
      #pragma unroll
      for (int e = 0; e < 4; ++e) {
        if (t0 + c8 + e < OUTL)     op[e]     = v0[e];
        if (t0 + c8 + 4 + e < OUTL) op[4 + e] = v1[e];
      }
    }
  }
}

extern "C" void kernel_launch(void* const* d_in, const int* in_sizes, int n_in,
                              void* d_out, int out_size, void* d_ws, size_t ws_size,
                              hipStream_t stream) {
  const float* x    = (const float*)d_in[0];
  const float* off  = (const float*)d_in[1];
  const float* wgt  = (const float*)d_in[2];
  const float* bias = (const float*)d_in[3];
  float* out  = (float*)d_out;
  short* ap   = (short*)d_ws;   // 393216 B of scratch

  // pack weights into coalesced fragment layout (~3 us)
  pack_weights_kernel<<<dim3(NQ * 2 * 8 * 64 / 256), dim3(256), 0, stream>>>(wgt, ap);
  // 8 b x 32 tt x 2 th = 512 blocks (2/CU), 512 threads (8 waves)
  deform_gemm_kernel<<<dim3(512), dim3(512), 0, stream>>>(x, off, ap, bias, out);
}

// Round 23
// 41.869 us; speedup vs baseline: 1.2481x; 1.2481x over previous
//
#include <hip/hip_runtime.h>
#include <stdint.h>

// DeformConv1d: x[8,256,4096] f32, offsets[8,1,4094,3] f32,
// weight[256,256,3] f32, bias[256] f32 -> out[8,256,4094] f32.
//
// R23: recombination of the measured-cheap pieces.
//  - Xt[68][256] transposed bf16 window, BOTH c-halves, staged ONCE
//    (burst-immediate: 3 rounds of load-3/write-3; no regs held).
//  - Bp build per tap over full 256 c: R15's b128 path (8 reads + 4
//    writes per thread) vs R20's 32 scalar gathers.
//  - K-loop: 8 barrier-free chunks per tap; 7 barriers total pre-epilogue
//    (R20 had ~13).
//  - launch_bounds(512,3): VGPR cap ~85. LDS 68.6KB caps blocks at 2/CU
//    anyway, so the higher reg budget costs no occupancy (R20's 64-cap
//    squeezed build temps; R15/R16/R21 spilled there).
// Kept verbatim: 32x32x16 MFMA + wave-private A from L2 + 1-ahead
// prefetch (R14 pack layout), R20 epilogue (WRITE == output), register
// meta, XCD-chunked decode, grid 512 x 512.

constexpr int CIN  = 256;
constexpr int LX   = 4096;
constexpr int KT   = 3;
constexpr int OUTL = 4094;
constexpr int COUT = 256;
constexpr int NQ   = 24;    // K-chunks of 32
constexpr int EPIW = 68;    // padded epilogue row (floats)
constexpr int CW   = 256;   // Xt/Bp row width (shorts)
constexpr int NST  = 4352;  // 256 c * 17 float4-groups

typedef __attribute__((ext_vector_type(8))) short bf16x8;
typedef __attribute__((ext_vector_type(4))) float f32x4;
typedef __attribute__((ext_vector_type(16))) float f32x16;

__device__ __forceinline__ short f2bf(float f) {        // round-half-up
  union { float f; uint32_t u; } v; v.f = f;
  return (short)((v.u + 0x8000u) >> 16);
}
__device__ __forceinline__ float bf2f(short s) {
  union { uint32_t u; float f; } v;
  v.u = ((uint32_t)(uint16_t)s) << 16;
  return v.f;
}
__device__ __forceinline__ float4 loadx4(const float* p, int l) {
  if (l + 3 < LX) return *(const float4*)(p + l);   // l is 16B-aligned
  float4 v; v.x = v.y = v.z = v.w = 0.f;
  if (l + 0 < LX) v.x = p[l + 0];
  if (l + 1 < LX) v.y = p[l + 1];
  if (l + 2 < LX) v.z = p[l + 2];
  return v;
}

// Weight pack (verbatim R14+): shorts idx = ((q*2+h)*8 + mf)*512 + l*8 + j
//   o = mf*32 + (l&31); c = ch*128 + (ks&3)*32 + h*16 + (l>>5)*8 + j;
//   tap = (q%12)>>2. Wave mf's K16-slice (q,h) = ONE coalesced 1KB load.
__global__ __launch_bounds__(256) void pack_weights_kernel(
    const float* __restrict__ w, short* __restrict__ ap) {
  const int gid = blockIdx.x * 256 + threadIdx.x;
  if (gid >= NQ * 2 * 8 * 64) return;
  const int l   = gid & 63;
  const int mf  = (gid >> 6) & 7;
  const int h   = (gid >> 9) & 1;
  const int q   = gid >> 10;
  const int ch  = q / 12;
  const int ks  = q % 12;
  const int tap = ks >> 2;
  const int c0  = ch * 128 + (ks & 3) * 32 + h * 16 + (l >> 5) * 8;
  const int row = mf * 32 + (l & 31);
  bf16x8 v;
  #pragma unroll
  for (int j = 0; j < 8; ++j) {
    v[j] = f2bf(w[((size_t)row * CIN + c0 + j) * KT + tap]);
  }
  *(bf16x8*)(ap + (size_t)gid * 8) = v;
}

__global__ __launch_bounds__(512, 3) void deform_gemm_kernel(
    const float* __restrict__ x, const float* __restrict__ off,
    const short* __restrict__ ap, const float* __restrict__ bias,
    float* __restrict__ out) {

  // arena: [0,34816) Xt bf16 [68][256] swz / Epi f32 [64][68] (reuse),
  //        [34816,67584) Bp bf16 [64][256] swz, [67584,68608) biasS
  __shared__ __align__(16) char smem[34816 + 32768 + 1024];
  short* Xt    = (short*)smem;
  short* Bp    = (short*)(smem + 34816);
  float* Epi   = (float*)smem;
  float* biasS = (float*)(smem + 67584);

  const int tid  = threadIdx.x;
  const int lane = tid & 63;
  const int wid  = tid >> 6;       // 0..7 = M-frag index (o rows wid*32..)
  const int l31  = lane & 31;
  const int lh   = lane >> 5;      // k-half within fragment

  // decode: b in low 3 bits (XCD-chunk); th pairs at bid stride 8
  const int b    = blockIdx.x & 7;        // 8 batches
  const int rest = blockIdx.x >> 3;       // 0..63
  const int th   = rest & 1;              // t-half
  const int tt   = rest >> 1;             // 32 coarse t-tiles
  const int t0   = tt * 128 + th * 64;

  // ---- per-thread interp meta for the Bp build (t = t0 + (tid&63)) ----
  float w0m[3], w1m[3];
  int   d0m[3];
  {
    const int t = t0 + (tid & 63);
    #pragma unroll
    for (int k = 0; k < KT; ++k) {
      float w0 = 0.f, w1 = 0.f; int d0 = 0;
      if (t < OUTL) {
        const float o = off[((size_t)b * OUTL + t) * KT + k];
        float T = (float)(t + k) + o;
        T = fminf(fmaxf(T, (float)t), (float)(t + 2));  // clip to [t, t+2]
        int U0 = (int)T;                                 // floor (T >= 0)
        if (U0 > LX - 2) U0 = LX - 2;
        w1 = T - (float)U0;                              // in [0,1]
        w0 = 1.f - w1;
        d0 = U0 - t0;                                    // in [0, 66]
      }
      w0m[k] = w0; w1m[k] = w1; d0m[k] = d0;
    }
  }
  if (tid < COUT) biasS[tid] = bias[tid];

  f32x16 acc0 = {0.f,0.f,0.f,0.f,0.f,0.f,0.f,0.f,0.f,0.f,0.f,0.f,0.f,0.f,0.f,0.f};
  f32x16 acc1 = {0.f,0.f,0.f,0.f,0.f,0.f,0.f,0.f,0.f,0.f,0.f,0.f,0.f,0.f,0.f,0.f};

  const float* xb = x + (size_t)b * CIN * LX;

  // A: wave-private coalesced loads; preload chunk q=0 (both K16 halves)
  const short* apw = ap + wid * 512 + lane * 8;
  bf16x8 aC0 = *(const bf16x8*)apw;
  bf16x8 aC1 = *(const bf16x8*)(apw + 4096);

  // ---- stage BOTH c-halves, transposed bf16, burst 3x3 (no held regs) --
  // idx -> c = idx/17 (0..255), g = idx%17; write pos = 4g+e at column c.
  // swizzle: short-index ^ ((pos&15)<<3) — XOR bits 3..6, write addr
  // computed as (pos*CW + c): c < 8-granule intact ((a+b)^s == (a^s)+b
  // for b<8, s multiple of 8 — verified by example, R8 lesson).
  #pragma unroll
  for (int rb = 0; rb < 3; ++rb) {
    float4 xv[3]; int cc[3], gg[3];
    #pragma unroll
    for (int j = 0; j < 3; ++j) {
      const int idx = (rb * 3 + j) * 512 + tid;
      if (idx < NST) {
        cc[j] = idx / 17; gg[j] = idx - cc[j] * 17;
        xv[j] = loadx4(xb + (size_t)cc[j] * LX, t0 + 4 * gg[j]);
      }
    }
    #pragma unroll
    for (int j = 0; j < 3; ++j) {
      const int idx = (rb * 3 + j) * 512 + tid;
      if (idx < NST) {
        const float fe[4] = {xv[j].x, xv[j].y, xv[j].z, xv[j].w};
        #pragma unroll
        for (int e = 0; e < 4; ++e) {
          const int pos = gg[j] * 4 + e;
          Xt[(pos * CW + cc[j]) ^ ((pos & 15) << 3)] = f2bf(fe[e]);
        }
      }
    }
  }
  __syncthreads();  // window + bias visible

  #pragma unroll
  for (int tap = 0; tap < KT; ++tap) {      // UNROLLED: static meta index
    if (tap) __syncthreads();               // prev tap's Bp readers done

    // ---- build Bp[t][c] (64t x 256c, swizzled): R15 b128 path ----
    // thread: t = tid&63, c-range = wid*32 .. +31 (4 granules of 8)
    {
      const int tq  = tid & 63;
      const int cb0 = wid * 32;
      const float w0 = w0m[tap], w1 = w1m[tap];
      const int   d0 = d0m[tap];
      const int r0i = d0 * CW, r1i = (d0 + 1) * CW;
      const int s0  = (d0 & 15) << 3;
      const int s1  = ((d0 + 1) & 15) << 3;
      const int st  = (tq & 15) << 3;
      #pragma unroll
      for (int g = 0; g < 4; ++g) {
        const int cb = cb0 + g * 8;
        const bf16x8 ra = *(const bf16x8*)&Xt[(r0i + cb) ^ s0];
        const bf16x8 rb = *(const bf16x8*)&Xt[(r1i + cb) ^ s1];
        bf16x8 o;
        #pragma unroll
        for (int j = 0; j < 8; ++j)
          o[j] = f2bf(bf2f(ra[j]) * w0 + bf2f(rb[j]) * w1);
        *(bf16x8*)&Bp[(tq * CW + cb) ^ st] = o;
      }
    }
    __syncthreads();  // Bp(tap) ready

    // ---- 8 barrier-free K-chunks (K=32 each; c spans 0..255) ----
    #pragma unroll 1
    for (int kc = 0; kc < 8; ++kc) {
      const int q  = tap * 4 + (kc >> 2) * 12 + (kc & 3);
      const int kn = kc + 1;
      const int qn = (kc < 7) ? (tap * 4 + (kn >> 2) * 12 + (kn & 3))
                              : (tap < 2 ? (tap + 1) * 4 : q);
      // prefetch next chunk's A (wave-private, L2-hot)
      const bf16x8 aN0 = *(const bf16x8*)(apw + (size_t)qn * 8192);
      const bf16x8 aN1 = *(const bf16x8*)(apw + (size_t)qn * 8192 + 4096);

      // B-frags: lane = col t' = jn*32+l31; elem j -> c = cg + j (+16)
      const int cg = (kc >> 2) * 128 + (kc & 3) * 32 + lh * 8;
      const int ta = l31,      swa = (ta & 15) << 3;  // jn = 0
      const int tb = 32 + l31, swb = (tb & 15) << 3;  // jn = 1
      {
        const bf16x8 b00 = *(const bf16x8*)&Bp[(ta * CW + cg) ^ swa];
        const bf16x8 b10 = *(const bf16x8*)&Bp[(tb * CW + cg) ^ swb];
        acc0 = __builtin_amdgcn_mfma_f32_32x32x16_bf16(aC0, b00, acc0, 0, 0, 0);
        acc1 = __builtin_amdgcn_mfma_f32_32x32x16_bf16(aC0, b10, acc1, 0, 0, 0);
      }
      {
        const bf16x8 b01 = *(const bf16x8*)&Bp[(ta * CW + cg + 16) ^ swa];
        const bf16x8 b11 = *(const bf16x8*)&Bp[(tb * CW + cg + 16) ^ swb];
        acc0 = __builtin_amdgcn_mfma_f32_32x32x16_bf16(aC1, b01, acc0, 0, 0, 0);
        acc1 = __builtin_amdgcn_mfma_f32_32x32x16_bf16(aC1, b11, acc1, 0, 0, 0);
      }
      aC0 = aN0; aC1 = aN1;
    }
  }

  // ---- epilogue: R20-verbatim (LDS-staged 256B row-segment stores) ----
  // 4 passes of 64 o-rows; producers = waves 2p, 2p+1 (their own M-frags).
  // 32x32 C/D layout: col = lane&31, row = (r&3) + 8*(r>>2) + 4*(lane>>5).
  const size_t obase = (size_t)b * COUT * OUTL;
  #pragma unroll
  for (int p = 0; p < 4; ++p) {
    __syncthreads();   // p==0: Bp readers done, Xt->Epi reuse safe
    if ((wid >> 1) == p) {
      const int lrb = (wid & 1) * 32;
      #pragma unroll
      for (int r = 0; r < 16; ++r) {
        const int rowl = (r & 3) + 8 * (r >> 2) + 4 * lh;   // 0..31
        const int grow = p * 64 + lrb + rowl;               // == wid*32+rowl
        Epi[(lrb + rowl) * EPIW + l31]      = acc0[r] + biasS[grow];
        Epi[(lrb + rowl) * EPIW + 32 + l31] = acc1[r] + biasS[grow];
      }
    }
    __syncthreads();
    // consumer: 512 threads, 64 x 64 f32 tile; 32B per thread
    const int rr = tid >> 3;               // 0..63
    const int c8 = (tid & 7) * 8;          // 0..56
    float* op = out + obase + (size_t)(p * 64 + rr) * OUTL + t0 + c8;
    const f32x4 v0 = *(const f32x4*)&Epi[rr * EPIW + c8];
    const f32x4 v1 = *(const f32x4*)&Epi[rr * EPIW + c8 + 4];
    if (t0 + c8 + 7 < OUTL) {
      *(f32x4*)op = v0;
      *(f32x4*)(op + 4) = v1;
    } else {
      #pragma unroll
      for (int e = 0; e < 4; ++e) {
        if (t0 + c8 + e < OUTL)     op[e]     = v0[e];
        if (t0 + c8 + 4 + e < OUTL) op[4 + e] = v1[e];
      }
    }
  }
}

extern "C" void kernel_launch(void* const* d_in, const int* in_sizes, int n_in,
                              void* d_out, int out_size, void* d_ws, size_t ws_size,
                              hipStream_t stream) {
  const float* x    = (const float*)d_in[0];
  const float* off  = (const float*)d_in[1];
  const float* wgt  = (const float*)d_in[2];
  const float* bias = (const float*)d_in[3];
  float* out  = (float*)d_out;
  short* ap   = (short*)d_ws;   // 393216 B of scratch

  // pack weights into coalesced fragment layout (~3 us)
  pack_weights_kernel<<<dim3(NQ * 2 * 8 * 64 / 256), dim3(256), 0, stream>>>(wgt, ap);
  // 8 b x 32 tt x 2 th = 512 blocks (2/CU), 512 threads (8 waves)
  deform_gemm_kernel<<<dim3(512), dim3(512), 0, stream>>>(x, off, ap, bias, out);
}